// Round 4
// baseline (6525.690 us; speedup 1.0000x reference)
//
#include <hip/hip_runtime.h>

#define TT 16384
#define BB 8
#define HH 512
#define CC 24
#define KK 100

// ---------------- GEMM: scoresT[b,c,t] = hs[b,t,:] @ W[:,c] + b[c] ----------------
__global__ __launch_bounds__(256) void score_gemm(
    const float* __restrict__ hs, const float* __restrict__ W,
    const float* __restrict__ bias, float* __restrict__ scoresT) {
  const long row = (long)blockIdx.x * 256 + threadIdx.x;
  const int b = (int)(row >> 14);   // TT = 16384 = 2^14
  const int t = (int)(row & (TT - 1));
  const float* x = hs + row * HH;
  float acc[CC];
#pragma unroll
  for (int c = 0; c < CC; ++c) acc[c] = bias[c];
#pragma unroll 2
  for (int h0 = 0; h0 < HH; h0 += 4) {
    float4 xv = *reinterpret_cast<const float4*>(x + h0);
    const float* wp = W + h0 * CC;
#pragma unroll
    for (int c = 0; c < CC; ++c) acc[c] = fmaf(xv.x, wp[c], acc[c]);
#pragma unroll
    for (int c = 0; c < CC; ++c) acc[c] = fmaf(xv.y, wp[CC + c], acc[c]);
#pragma unroll
    for (int c = 0; c < CC; ++c) acc[c] = fmaf(xv.z, wp[2 * CC + c], acc[c]);
#pragma unroll
    for (int c = 0; c < CC; ++c) acc[c] = fmaf(xv.w, wp[3 * CC + c], acc[c]);
  }
  float* op = scoresT + (long)b * CC * TT + t;
#pragma unroll
  for (int c = 0; c < CC; ++c) op[(long)c * TT] = acc[c];
}

// ---------------- DPP helpers (VALU pipe) ----------------
// 0x111 = row_shr:1 (lane l <- lane l-1 in 16-lane row); 0xB1 = quad_perm [1,0,3,2]
template <int CTRL>
__device__ __forceinline__ float dpp_mov(float x) {
  return __int_as_float(__builtin_amdgcn_update_dpp(
      __float_as_int(x), __float_as_int(x), CTRL, 0xF, 0xF, false));
}

// ---------------- Streaming semi-Markov CRF scan — readlane broadcast ----------------
// One wave per batch. Lane pair (2c,2c+1) owns channel c; even lane: taps k=1..50,
// odd lane: taps k=51..100. Exp-domain recurrence with lag-2 global scale P
// (P_i = exact max-alpha from 2 steps earlier). NO LDS: the 24-channel all-to-all
// is done with 24 v_readlane broadcasts (even lanes) -> SGPRs; the msg matvec is
// 24 v_fma with SGPR x VGPR operands per lane (eTall[q] = exp(trans[q][c])).
// Global max for the lagged P is a SALU s_max_u32 tree over the readlane bit
// patterns (positive floats order as unsigned ints). Window taps are
// piecewise-rescaled per 4-step macro with static re-indexing (E[49] + X[4]).
// Chain/step: S -> mul f -> fma w0 -> DPP pair-sum -> mul g -> e -> 24 readlane
//            -> 3-deep fma chains -> S.
__global__ __launch_bounds__(64) void crf_scan(
    const float* __restrict__ scoresT, const float* __restrict__ trans,
    const float* __restrict__ db, const int* __restrict__ lengths,
    float* __restrict__ out) {
  const int b = blockIdx.x;
  const int lane = threadIdx.x;  // 0..63
  const int c = lane >> 1;       // channel (>=24 idle)
  const int par = lane & 1;
  const bool act = (c < CC);
  const int cc = act ? c : 0;

  // duration weights: w[q] = exp(db[par*50 + q][c])  (k-1 = par*50+q)
  float w[50];
  const int kb = par * 50;
#pragma unroll
  for (int q = 0; q < 50; ++q) w[q] = act ? __expf(db[(kb + q) * CC + cc]) : 0.0f;
  const float w0e = (par == 0) ? w[0] : 0.0f;  // even lane's k=1 weight
  const float w0o = (par == 1) ? w[0] : 0.0f;  // odd lane's k=51 weight (X[u] term)

  // full transition column for own channel: eTall[q] = exp(trans[q][c]), q=0..23
  float eTall[24];
#pragma unroll
  for (int q = 0; q < 24; ++q)
    eTall[q] = act ? __expf(trans[q * CC + cc]) : 0.0f;

  int len = lengths[b];
  len = len < 1 ? 1 : (len > TT ? TT : len);

  // Window state (scale M, fixed within a macro-iter):
  // even: E[q] = scaled exp(u_{i0-2-q});  odd: E[q] = u_{i0-52-q}.
  // X[m]: even = enew born at sub-step m; odd = boundary taps B[m].
  float E[49], X[4];
#pragma unroll
  for (int q = 0; q < 49; ++q) E[q] = 0.0f;
#pragma unroll
  for (int m = 0; m < 4; ++m) X[m] = 0.0f;

  float cum = 0.0f;    // running per-channel cum (pair-redundant)
  float M = -30.0f;    // window scale (piecewise constant)
  float S = 1.0f;      // matvec result of previous step (chain carrier)
  float P0 = 0.0f, P1 = 0.0f, Pprev = 0.0f;    // lagged global scales P_i = am_{i-2}
  float Pu2 = 0.0f, S2s = 1.0f, cum2s = 0.0f;  // saved at sub-step 2 for u_lag

  const float4* sp4 =
      reinterpret_cast<const float4*>(scoresT + ((long)b * CC + cc) * TT);
  float4 buf0 = sp4[0];
  float4 buf1 = sp4[1];
  const int NJ = TT / 4;

  for (int j = 0; j < NJ; ++j) {
    int jn = j + 2;
    jn = jn < NJ ? jn : NJ - 1;
    float4 nb = sp4[jn];  // 8-step prefetch distance
    float scs[4] = {buf0.x, buf0.y, buf0.z, buf0.w};
#pragma unroll
    for (int u = 0; u < 4; ++u) {
      const float P_used = P0;
      // off-chain scale factors (inputs are lagged / already known)
      float f = __expf(fminf(Pprev - cum - M, 80.0f));  // cum here = cum_{i-1}
      cum += scs[u];
      float g = __expf(fminf(cum + M - P_used, 80.0f));

      // window dot (off-chain): E/X taps with static indices
      float ch[4] = {0.0f, 0.0f, 0.0f, 0.0f};
#pragma unroll
      for (int q = 0; q <= 48 - u; ++q)
        ch[q & 3] = fmaf(E[q], w[u + 1 + q], ch[q & 3]);
#pragma unroll
      for (int m = 0; m <= u; ++m)  // X taps; m==u term: odd's B[u] (even: *0)
        ch[m & 3] = fmaf(X[m], (m == u) ? w0o : w[u - m], ch[m & 3]);
      float rest = (ch[0] + ch[1]) + (ch[2] + ch[3]);

      float enew = S * f;               // CHAIN
      float s = fmaf(enew, w0e, rest);  // CHAIN (odd adds 0)
      s += dpp_mov<0xB1>(s);            // CHAIN: pair total = full 100-tap sum
      float e = s * g;                  // CHAIN: e = exp(alpha - P_used)
      X[u] = par ? X[u] : enew;         // off-chain: record newborn tap (even only)

      // broadcast all 24 channel e-values via readlane (VALU; no LDS)
      float vs[24];
      unsigned us[24];
#pragma unroll
      for (int q = 0; q < 24; ++q) {
        int bits = __builtin_amdgcn_readlane(__float_as_int(e), 2 * q);
        vs[q] = __int_as_float(bits);
        us[q] = (unsigned)bits;
      }

      // msg matvec: Sn = sum_q vs[q] * exp(trans[q][c]); 8 parallel fma chains
      float a0 = vs[0] * eTall[0], a1 = vs[1] * eTall[1];
      float a2 = vs[2] * eTall[2], a3 = vs[3] * eTall[3];
      float a4 = vs[4] * eTall[4], a5 = vs[5] * eTall[5];
      float a6 = vs[6] * eTall[6], a7 = vs[7] * eTall[7];
#pragma unroll
      for (int q = 8; q < 24; q += 8) {
        a0 = fmaf(vs[q + 0], eTall[q + 0], a0);
        a1 = fmaf(vs[q + 1], eTall[q + 1], a1);
        a2 = fmaf(vs[q + 2], eTall[q + 2], a2);
        a3 = fmaf(vs[q + 3], eTall[q + 3], a3);
        a4 = fmaf(vs[q + 4], eTall[q + 4], a4);
        a5 = fmaf(vs[q + 5], eTall[q + 5], a5);
        a6 = fmaf(vs[q + 6], eTall[q + 6], a6);
        a7 = fmaf(vs[q + 7], eTall[q + 7], a7);
      }
      float Sn = ((a0 + a1) + (a2 + a3)) + ((a4 + a5) + (a6 + a7));

      // off-chain: exact max-alpha via SALU u32 max (positive floats order as uint)
      unsigned um = us[0];
#pragma unroll
      for (int q = 1; q < 24; ++q) um = um > us[q] ? um : us[q];
      float am = P_used + __logf(__uint_as_float(um));  // = max_c alpha_c (exact)

      if (4 * j + u == len - 1) {  // partition = P + log(sum_c e_c); uniform branch
        float se = (((vs[0] + vs[1]) + (vs[2] + vs[3])) +
                    ((vs[4] + vs[5]) + (vs[6] + vs[7]))) +
                   (((vs[8] + vs[9]) + (vs[10] + vs[11])) +
                    ((vs[12] + vs[13]) + (vs[14] + vs[15]))) +
                   (((vs[16] + vs[17]) + (vs[18] + vs[19])) +
                    ((vs[20] + vs[21]) + (vs[22] + vs[23])));
        if (lane == 0) out[b] = P_used + __logf(se);
        return;
      }

      S = Sn;
      Pprev = P_used;
      P0 = P1;
      P1 = am;
      if (u == 2) { Pu2 = P_used; S2s = Sn; cum2s = cum; }
    }

    // ---- macro boundary: M update + rotate/rescale window by 4 taps ----
    float u_lag = Pu2 + __logf(S2s) - cum2s;  // u_{i0+2} (lag-2 at next use)
    float Mn = fmaxf(M - 0.0625f, u_lag - 20.0f);
    float r4 = __expf(M - Mn);
    M = Mn;
    float D0 = dpp_mov<0x111>(E[42]);  // even->odd boundary taps (valid on odd lanes)
    float D1 = dpp_mov<0x111>(E[43]);
    float D2 = dpp_mov<0x111>(E[44]);
    float D3 = dpp_mov<0x111>(E[45]);
#pragma unroll
    for (int q = 48; q >= 4; --q) E[q] = E[q - 4] * r4;
    E[0] = (par ? D0 : X[3]) * r4;
    E[1] = (par ? D1 : X[2]) * r4;
    E[2] = (par ? D2 : X[1]) * r4;
    E[3] = (par ? D3 : X[0]) * r4;
    X[0] = D3 * r4;  // odd's new B[0..3]; even lanes overwrite during sub-steps
    X[1] = D2 * r4;
    X[2] = D1 * r4;
    X[3] = D0 * r4;
    buf0 = buf1;
    buf1 = nb;
  }
}

extern "C" void kernel_launch(void* const* d_in, const int* in_sizes, int n_in,
                              void* d_out, int out_size, void* d_ws, size_t ws_size,
                              hipStream_t stream) {
  const float* hs = (const float*)d_in[0];       // (B,T,H) f32
  const float* W = (const float*)d_in[1];        // (H,C) f32
  const float* bias = (const float*)d_in[2];     // (C,) f32
  const float* trans = (const float*)d_in[3];    // (C,C) f32
  const float* db = (const float*)d_in[4];       // (K,C) f32
  const int* lengths = (const int*)d_in[5];      // (B,) i32
  float* scoresT = (float*)d_ws;                 // (B,C,T) f32 scratch

  score_gemm<<<(BB * TT) / 256, 256, 0, stream>>>(hs, W, bias, scoresT);
  crf_scan<<<BB, 64, 0, stream>>>(scoresT, trans, db, lengths, (float*)d_out);
}

// Round 5
// 5321.417 us; speedup vs baseline: 1.2263x; 1.2263x over previous
//
#include <hip/hip_runtime.h>

#define TT 16384
#define BB 8
#define HH 512
#define CC 24
#define KK 100

// ---------------- GEMM: scoresT[b,c,t] = hs[b,t,:] @ W[:,c] + b[c] ----------------
__global__ __launch_bounds__(256) void score_gemm(
    const float* __restrict__ hs, const float* __restrict__ W,
    const float* __restrict__ bias, float* __restrict__ scoresT) {
  const long row = (long)blockIdx.x * 256 + threadIdx.x;
  const int b = (int)(row >> 14);   // TT = 16384 = 2^14
  const int t = (int)(row & (TT - 1));
  const float* x = hs + row * HH;
  float acc[CC];
#pragma unroll
  for (int c = 0; c < CC; ++c) acc[c] = bias[c];
#pragma unroll 2
  for (int h0 = 0; h0 < HH; h0 += 4) {
    float4 xv = *reinterpret_cast<const float4*>(x + h0);
    const float* wp = W + h0 * CC;
#pragma unroll
    for (int c = 0; c < CC; ++c) acc[c] = fmaf(xv.x, wp[c], acc[c]);
#pragma unroll
    for (int c = 0; c < CC; ++c) acc[c] = fmaf(xv.y, wp[CC + c], acc[c]);
#pragma unroll
    for (int c = 0; c < CC; ++c) acc[c] = fmaf(xv.z, wp[2 * CC + c], acc[c]);
#pragma unroll
    for (int c = 0; c < CC; ++c) acc[c] = fmaf(xv.w, wp[3 * CC + c], acc[c]);
  }
  float* op = scoresT + (long)b * CC * TT + t;
#pragma unroll
  for (int c = 0; c < CC; ++c) op[(long)c * TT] = acc[c];
}

// ---------------- DPP helpers (VALU pipe) ----------------
// 0x111 = row_shr:1 (lane l <- lane l-1 in 16-lane row); 0xB1 = quad_perm [1,0,3,2]
template <int CTRL>
__device__ __forceinline__ float dpp_mov(float x) {
  return __int_as_float(__builtin_amdgcn_update_dpp(
      __float_as_int(x), __float_as_int(x), CTRL, 0xF, 0xF, false));
}

// ---------------- Streaming semi-Markov CRF scan ----------------
// One wave per batch. Lane pair (2c,2c+1) owns channel c; even: taps k=1..50,
// trans rows 0..11; odd: taps k=51..100, trans rows 12..23. Exp-domain chain with
// lag-2 global scale P. LDS broadcast of e (unconditional per-lane-constant slot,
// no exec masking). MAIN LOOP IS BRANCH-FREE: jexit=(len-1)>>2 full macro-iters
// with no exit checks (compiler can hoist off-chain work across sub-steps);
// a <=4-step epilogue does the length check and writes the partition.
__global__ __launch_bounds__(64) void crf_scan(
    const float* __restrict__ scoresT, const float* __restrict__ trans,
    const float* __restrict__ db, const int* __restrict__ lengths,
    float* __restrict__ out) {
  const int b = blockIdx.x;
  const int lane = threadIdx.x;  // 0..63
  const int c = lane >> 1;       // channel (>=24 idle)
  const int par = lane & 1;
  const bool act = (c < CC);
  const int cc = act ? c : 0;

  __shared__ float lds_e[32];
  // per-lane-constant store slot: even active lanes -> own channel, rest -> dump 31
  const int eslot = (par == 0 && act) ? c : 31;

  // duration weights: w[q] = exp(db[par*50 + q][c])
  float w[50];
  const int kb = par * 50;
#pragma unroll
  for (int q = 0; q < 50; ++q) w[q] = act ? __expf(db[(kb + q) * CC + cc]) : 0.0f;
  const float w0e = (par == 0) ? w[0] : 0.0f;
  const float w0o = (par == 1) ? w[0] : 0.0f;

  float eT[12];
#pragma unroll
  for (int q = 0; q < 12; ++q)
    eT[q] = act ? __expf(trans[(par * 12 + q) * CC + cc]) : 0.0f;

  int len = lengths[b];
  len = len < 1 ? 1 : (len > TT ? TT : len);
  const int jexit = (len - 1) >> 2;  // main-loop macro count (branch-free region)

  // Window state (scale M fixed within a macro):
  // even: E[q] = scaled exp(u_{i0-2-q}); odd: E[q] = u_{i0-52-q}.
  // X[m]: even = enew born at sub-step m; odd = boundary taps B[m].
  float E[49], X[4];
#pragma unroll
  for (int q = 0; q < 49; ++q) E[q] = 0.0f;
#pragma unroll
  for (int m = 0; m < 4; ++m) X[m] = 0.0f;

  float cum = 0.0f;    // running per-channel cum (pair-redundant)
  float M = -30.0f;    // window scale (piecewise constant per macro)
  float S = 1.0f;      // prev-step matvec result (chain carrier); S_{-1}=1 with P=0
  float P0 = 0.0f, P1 = 0.0f, Pprev = 0.0f;    // lagged scales P_i = am_{i-2}
  float Pu2 = 0.0f, S2s = 1.0f, cum2s = 0.0f;  // saved at sub-step 2 for u_lag

  const float4* sp4 =
      reinterpret_cast<const float4*>(scoresT + ((long)b * CC + cc) * TT);
  float4 buf0 = sp4[0];
  float4 buf1 = sp4[1];
  const int NJ = TT / 4;
  const float4* pe = reinterpret_cast<const float4*>(lds_e) + par * 3;

  for (int j = 0; j < jexit; ++j) {  // ---- branch-free main loop ----
    int jn = j + 2;
    jn = jn < NJ ? jn : NJ - 1;
    float4 nb = sp4[jn];  // 8-step prefetch distance
    float scs[4] = {buf0.x, buf0.y, buf0.z, buf0.w};
#pragma unroll
    for (int u = 0; u < 4; ++u) {
      const float P_used = P0;
      float f = __expf(fminf(Pprev - cum - M, 80.0f));  // cum = cum_{i-1}
      cum += scs[u];
      float g = __expf(fminf(cum + M - P_used, 80.0f));

      // window dot (off-chain): static tap indices
      float ch[4] = {0.0f, 0.0f, 0.0f, 0.0f};
#pragma unroll
      for (int q = 0; q <= 48 - u; ++q)
        ch[q & 3] = fmaf(E[q], w[u + 1 + q], ch[q & 3]);
#pragma unroll
      for (int m = 0; m <= u; ++m)
        ch[m & 3] = fmaf(X[m], (m == u) ? w0o : w[u - m], ch[m & 3]);
      float rest = (ch[0] + ch[1]) + (ch[2] + ch[3]);

      float enew = S * f;               // CHAIN
      float s = fmaf(enew, w0e, rest);  // CHAIN
      s += dpp_mov<0xB1>(s);            // CHAIN: pair total (100 taps)
      float e = s * g;                  // CHAIN: e = exp(alpha - P_used)
      X[u] = par ? X[u] : enew;         // off-chain

      lds_e[eslot] = e;                 // unconditional, per-lane-constant slot
      __builtin_amdgcn_wave_barrier();  // DS pipe in-order within a wave
      float4 e0 = pe[0], e1 = pe[1], e2 = pe[2];  // CHAIN: 12 e-values

      float S0 = e0.x * eT[0], S1 = e0.y * eT[1];
      float S2v = e0.z * eT[2], S3 = e0.w * eT[3];
      S0 = fmaf(e1.x, eT[4], S0);
      S1 = fmaf(e1.y, eT[5], S1);
      S2v = fmaf(e1.z, eT[6], S2v);
      S3 = fmaf(e1.w, eT[7], S3);
      S0 = fmaf(e2.x, eT[8], S0);
      S1 = fmaf(e2.y, eT[9], S1);
      S2v = fmaf(e2.z, eT[10], S2v);
      S3 = fmaf(e2.w, eT[11], S3);
      float Sn = (S0 + S1) + (S2v + S3);
      Sn += dpp_mov<0xB1>(Sn);          // CHAIN: all 24 c'

      // off-chain: exact max-alpha (used as P two steps later)
      float mx = fmaxf(fmaxf(fmaxf(e0.x, e0.y), fmaxf(e0.z, e0.w)),
                       fmaxf(fmaxf(fmaxf(e1.x, e1.y), fmaxf(e1.z, e1.w)),
                             fmaxf(fmaxf(e2.x, e2.y), fmaxf(e2.z, e2.w))));
      mx = fmaxf(mx, dpp_mov<0xB1>(mx));
      float am = P_used + __logf(mx);

      S = Sn;
      Pprev = P_used;
      P0 = P1;
      P1 = am;
      if (u == 2) { Pu2 = P_used; S2s = Sn; cum2s = cum; }
    }

    // ---- macro boundary: M update + rotate/rescale window by 4 taps ----
    float u_lag = Pu2 + __logf(S2s) - cum2s;
    float Mn = fmaxf(M - 0.0625f, u_lag - 20.0f);
    float r4 = __expf(M - Mn);
    M = Mn;
    float D0 = dpp_mov<0x111>(E[42]);
    float D1 = dpp_mov<0x111>(E[43]);
    float D2 = dpp_mov<0x111>(E[44]);
    float D3 = dpp_mov<0x111>(E[45]);
#pragma unroll
    for (int q = 48; q >= 4; --q) E[q] = E[q - 4] * r4;
    E[0] = (par ? D0 : X[3]) * r4;
    E[1] = (par ? D1 : X[2]) * r4;
    E[2] = (par ? D2 : X[1]) * r4;
    E[3] = (par ? D3 : X[0]) * r4;
    X[0] = D3 * r4;
    X[1] = D2 * r4;
    X[2] = D1 * r4;
    X[3] = D0 * r4;
    buf0 = buf1;
    buf1 = nb;
  }

  // ---- epilogue: final 1..4 sub-steps with length check ----
  {
    const int ulast = (len - 1) & 3;
    float scs[4] = {buf0.x, buf0.y, buf0.z, buf0.w};
#pragma unroll
    for (int u = 0; u < 4; ++u) {
      const float P_used = P0;
      float f = __expf(fminf(Pprev - cum - M, 80.0f));
      cum += scs[u];
      float g = __expf(fminf(cum + M - P_used, 80.0f));

      float ch[4] = {0.0f, 0.0f, 0.0f, 0.0f};
#pragma unroll
      for (int q = 0; q <= 48 - u; ++q)
        ch[q & 3] = fmaf(E[q], w[u + 1 + q], ch[q & 3]);
#pragma unroll
      for (int m = 0; m <= u; ++m)
        ch[m & 3] = fmaf(X[m], (m == u) ? w0o : w[u - m], ch[m & 3]);
      float rest = (ch[0] + ch[1]) + (ch[2] + ch[3]);

      float enew = S * f;
      float s = fmaf(enew, w0e, rest);
      s += dpp_mov<0xB1>(s);
      float e = s * g;
      X[u] = par ? X[u] : enew;

      lds_e[eslot] = e;
      __builtin_amdgcn_wave_barrier();
      float4 e0 = pe[0], e1 = pe[1], e2 = pe[2];

      if (u == ulast) {  // partition = P + log(sum_c e_c); uniform branch
        float se = ((e0.x + e0.y) + (e0.z + e0.w)) +
                   ((e1.x + e1.y) + (e1.z + e1.w)) +
                   ((e2.x + e2.y) + (e2.z + e2.w));
        se += dpp_mov<0xB1>(se);
        if (lane == 0) out[b] = P_used + __logf(se);
        return;
      }

      float S0 = e0.x * eT[0], S1 = e0.y * eT[1];
      float S2v = e0.z * eT[2], S3 = e0.w * eT[3];
      S0 = fmaf(e1.x, eT[4], S0);
      S1 = fmaf(e1.y, eT[5], S1);
      S2v = fmaf(e1.z, eT[6], S2v);
      S3 = fmaf(e1.w, eT[7], S3);
      S0 = fmaf(e2.x, eT[8], S0);
      S1 = fmaf(e2.y, eT[9], S1);
      S2v = fmaf(e2.z, eT[10], S2v);
      S3 = fmaf(e2.w, eT[11], S3);
      float Sn = (S0 + S1) + (S2v + S3);
      Sn += dpp_mov<0xB1>(Sn);

      float mx = fmaxf(fmaxf(fmaxf(e0.x, e0.y), fmaxf(e0.z, e0.w)),
                       fmaxf(fmaxf(fmaxf(e1.x, e1.y), fmaxf(e1.z, e1.w)),
                             fmaxf(fmaxf(e2.x, e2.y), fmaxf(e2.z, e2.w))));
      mx = fmaxf(mx, dpp_mov<0xB1>(mx));
      float am = P_used + __logf(mx);

      S = Sn;
      Pprev = P_used;
      P0 = P1;
      P1 = am;
    }
  }
}

extern "C" void kernel_launch(void* const* d_in, const int* in_sizes, int n_in,
                              void* d_out, int out_size, void* d_ws, size_t ws_size,
                              hipStream_t stream) {
  const float* hs = (const float*)d_in[0];       // (B,T,H) f32
  const float* W = (const float*)d_in[1];        // (H,C) f32
  const float* bias = (const float*)d_in[2];     // (C,) f32
  const float* trans = (const float*)d_in[3];    // (C,C) f32
  const float* db = (const float*)d_in[4];       // (K,C) f32
  const int* lengths = (const int*)d_in[5];      // (B,) i32
  float* scoresT = (float*)d_ws;                 // (B,C,T) f32 scratch

  score_gemm<<<(BB * TT) / 256, 256, 0, stream>>>(hs, W, bias, scoresT);
  crf_scan<<<BB, 64, 0, stream>>>(scoresT, trans, db, lengths, (float*)d_out);
}